// Round 1
// baseline (372.511 us; speedup 1.0000x reference)
//
#include <hip/hip_runtime.h>
#include <hip/hip_bf16.h>

#define NPTS 131072
#define MCB  512
#define DIM  128
#define NRB  (NPTS/128)   // 1024 row blocks
#define NCBK (MCB/128)    // 4 col blocks
#define NBLK (NRB*NCBK)   // 4096 blocks

typedef __attribute__((ext_vector_type(4))) float  f32x4;
typedef __attribute__((ext_vector_type(8))) __bf16 bf16x8;
typedef unsigned short u16;
typedef unsigned int   u32;

// XOR-swizzle: permute 16B chunks within each 256B row by row&7.
// Involution; preserves bits >=8 and 16B alignment.
__device__ __forceinline__ u32 swz(u32 p) { return p ^ (((p >> 8) & 7u) << 4); }

// Convert f32 rows (length 128) to bf16, and emit per-row sum of squares of the
// ROUNDED values (so d2 == ||x_b - s_b||^2 exactly, up to f32 accumulation).
// One wave handles 2 rows per iteration: 32 lanes x float4 per row.
__global__ __launch_bounds__(256) void convert_rows(const float* __restrict__ in,
                                                    u16* __restrict__ outb,
                                                    float* __restrict__ sq,
                                                    int nrows) {
  int wv = threadIdx.x >> 6, ln = threadIdx.x & 63;
  int half = ln >> 5, li = ln & 31;
  int npairs = nrows >> 1;
  for (int pr = blockIdx.x * 4 + wv; pr < npairs; pr += gridDim.x * 4) {
    int row = pr * 2 + half;
    const float4 v = *(const float4*)(in + (size_t)row * DIM + li * 4);
    __hip_bfloat16 b0 = __float2bfloat16(v.x);
    __hip_bfloat16 b1 = __float2bfloat16(v.y);
    __hip_bfloat16 b2 = __float2bfloat16(v.z);
    __hip_bfloat16 b3 = __float2bfloat16(v.w);
    ushort4 o;
    o.x = *(const u16*)&b0; o.y = *(const u16*)&b1;
    o.z = *(const u16*)&b2; o.w = *(const u16*)&b3;
    *(ushort4*)(outb + (size_t)row * DIM + li * 4) = o;
    float f0 = __bfloat162float(b0), f1 = __bfloat162float(b1);
    float f2 = __bfloat162float(b2), f3 = __bfloat162float(b3);
    float s = f0 * f0 + f1 * f1 + f2 * f2 + f3 * f3;
    s += __shfl_xor(s, 1); s += __shfl_xor(s, 2); s += __shfl_xor(s, 4);
    s += __shfl_xor(s, 8); s += __shfl_xor(s, 16);
    if (li == 0) sq[row] = s;
  }
}

// One block = 128x128 output tile; K=128 fits in one LDS tile (no K loop).
// 4 waves in 2x2, each owns 64x64 (4x4 fragments of 16x16, 4 k-steps of 32).
// WRITE=0: accumulate per-column sums of exp(-dist) into partial[rb][m].
// WRITE=1: write exp(-dist) * inv_sum[m] to out.
template <int WRITE>
__global__ __launch_bounds__(256, 2) void gemm_pass(const u16* __restrict__ Xb,
                                                    const u16* __restrict__ Sb,
                                                    const float* __restrict__ x2,
                                                    const float* __restrict__ s2,
                                                    const float* __restrict__ invs,
                                                    float* __restrict__ outp) {
  __shared__ u16 At[128 * DIM];   // 32 KB, swizzled storage
  __shared__ u16 Bt[128 * DIM];   // 32 KB
  __shared__ float lx2[128], ls2[128], lscale[128], colsum[128];

  int t = threadIdx.x, wv = t >> 6, ln = t & 63;
  u32 h = blockIdx.x;
  u32 l = (h & 7u) * (NBLK / 8) + (h >> 3);   // bijective XCD chunking
  u32 rb = l >> 2, cb = l & 3u;
  u32 n0 = rb * 128, m0 = cb * 128;

  // Stage A/B tiles: each is one contiguous 32KB region (rows are contiguous,
  // K==row length). Pre-swizzle the GLOBAL source; LDS dest stays linear.
  const char* Ag = (const char*)(Xb + (size_t)n0 * DIM);
  const char* Bg = (const char*)(Sb + (size_t)m0 * DIM);
#pragma unroll
  for (int i = 0; i < 8; i++) {
    u32 c = i * 4 + wv;
    u32 lb = c * 1024;                 // wave-uniform LDS base
    u32 go = swz(lb + ln * 16);        // per-lane swizzled global offset
    __builtin_amdgcn_global_load_lds((const __attribute__((address_space(1))) void*)(Ag + go),
                                     (__attribute__((address_space(3))) void*)((char*)At + lb),
                                     16, 0, 0);
    __builtin_amdgcn_global_load_lds((const __attribute__((address_space(1))) void*)(Bg + go),
                                     (__attribute__((address_space(3))) void*)((char*)Bt + lb),
                                     16, 0, 0);
  }
  if (t < 128) {
    lx2[t] = x2[n0 + t];
    ls2[t] = s2[m0 + t];
    if (WRITE) lscale[t] = invs[m0 + t];
    else       colsum[t] = 0.f;
  }
  __syncthreads();

  int wr = wv >> 1, wc = wv & 1;
  int rbw = wr * 64, cbw = wc * 64;
  int lr = ln & 15, lg = ln >> 4;

  f32x4 acc[4][4];
#pragma unroll
  for (int i = 0; i < 4; i++)
#pragma unroll
    for (int j = 0; j < 4; j++) acc[i][j] = (f32x4){0.f, 0.f, 0.f, 0.f};

#pragma unroll
  for (int kk = 0; kk < 4; kk++) {
    bf16x8 af[4], bfr[4];
#pragma unroll
    for (int i = 0; i < 4; i++)
      af[i] = *(const bf16x8*)((const char*)At +
               swz((u32)((rbw + i * 16 + lr) * 256 + kk * 64 + lg * 16)));
#pragma unroll
    for (int j = 0; j < 4; j++)
      bfr[j] = *(const bf16x8*)((const char*)Bt +
               swz((u32)((cbw + j * 16 + lr) * 256 + kk * 64 + lg * 16)));
#pragma unroll
    for (int i = 0; i < 4; i++)
#pragma unroll
      for (int j = 0; j < 4; j++)
        acc[i][j] = __builtin_amdgcn_mfma_f32_16x16x32_bf16(af[i], bfr[j], acc[i][j], 0, 0, 0);
  }

  // Epilogue. C/D layout (m89-verified): col = lane&15, row = (lane>>4)*4 + reg.
  float csum[4] = {0.f, 0.f, 0.f, 0.f};
#pragma unroll
  for (int i = 0; i < 4; i++) {
#pragma unroll
    for (int j = 0; j < 4; j++) {
#pragma unroll
      for (int r = 0; r < 4; r++) {
        int nl = rbw + i * 16 + lg * 4 + r;
        int ml = cbw + j * 16 + lr;
        float d2 = lx2[nl] + ls2[ml] - 2.f * acc[i][j][r];
        d2 = fmaxf(d2, 0.f);
        float e = __expf(-__fsqrt_rn(d2));
        if (WRITE) {
          outp[(size_t)(n0 + nl) * MCB + (m0 + ml)] = e * lscale[ml];
        } else {
          csum[j] += e;
        }
      }
    }
  }
  if (!WRITE) {
    // csum[j] covers this wave's 64 rows for column (cbw + j*16 + lr),
    // spread over the 4 lane-groups -> combine with xor-16/32 shuffles.
#pragma unroll
    for (int j = 0; j < 4; j++) {
      float v = csum[j];
      v += __shfl_xor(v, 16);
      v += __shfl_xor(v, 32);
      if (ln < 16) atomicAdd(&colsum[cbw + j * 16 + ln], v);
    }
    __syncthreads();
    if (t < 128) outp[(size_t)rb * MCB + m0 + t] = colsum[t];  // partial sums
  }
}

// Sum the 1024 per-row-block partials per column, emit 1/sum. Deterministic.
__global__ __launch_bounds__(256) void reduce_cols(const float* __restrict__ partial,
                                                   float* __restrict__ invs) {
  int m = blockIdx.x, t = threadIdx.x;
  float s = 0.f;
  for (int k = t; k < NRB; k += 256) s += partial[(size_t)k * MCB + m];
  s += __shfl_xor(s, 1);  s += __shfl_xor(s, 2);  s += __shfl_xor(s, 4);
  s += __shfl_xor(s, 8);  s += __shfl_xor(s, 16); s += __shfl_xor(s, 32);
  __shared__ float w4[4];
  if ((t & 63) == 0) w4[t >> 6] = s;
  __syncthreads();
  if (t == 0) invs[m] = 1.0f / (w4[0] + w4[1] + w4[2] + w4[3]);
}

extern "C" void kernel_launch(void* const* d_in, const int* in_sizes, int n_in,
                              void* d_out, int out_size, void* d_ws, size_t ws_size,
                              hipStream_t stream) {
  const float* X = (const float*)d_in[0];
  const float* S = (const float*)d_in[1];
  float* out = (float*)d_out;
  char* ws = (char*)d_ws;

  // ws layout (all offsets 256B-aligned), total ~34.6 MB:
  u16*   Xb      = (u16*)ws;                      // 131072*128*2 = 33554432
  u16*   Sb      = (u16*)(ws + 33554432);         // 512*128*2    = 131072
  float* x2      = (float*)(ws + 33685504);       // 131072*4     = 524288
  float* s2      = (float*)(ws + 34209792);       // 512*4        = 2048
  float* invs    = (float*)(ws + 34211840);       // 512*4        = 2048
  float* partial = (float*)(ws + 34213888);       // 1024*512*4   = 2097152

  convert_rows<<<1024, 256, 0, stream>>>(X, Xb, x2, NPTS);
  convert_rows<<<64, 256, 0, stream>>>(S, Sb, s2, MCB);
  gemm_pass<0><<<NBLK, 256, 0, stream>>>(Xb, Sb, x2, s2, invs, partial);
  reduce_cols<<<MCB, 256, 0, stream>>>(partial, invs);
  gemm_pass<1><<<NBLK, 256, 0, stream>>>(Xb, Sb, x2, s2, invs, out);
}